// Round 14
// baseline (78.995 us; speedup 1.0000x reference)
//
#include <hip/hip_runtime.h>
#include <hip/hip_bf16.h>
#include <math.h>

#define B_ 8
#define C_ 256
#define N_ 1024
#define NH_ 8
#define HD_ 32

typedef __attribute__((ext_vector_type(8))) short bf16x8;
typedef __attribute__((ext_vector_type(4))) short bf16x4;
typedef __attribute__((ext_vector_type(4))) float f32x4;
typedef __attribute__((ext_vector_type(16))) float f32x16;
typedef __attribute__((ext_vector_type(2))) unsigned int u32x2;
typedef __attribute__((ext_vector_type(4))) unsigned int u32x4;
#define MFMA16(a,b,c) __builtin_amdgcn_mfma_f32_16x16x32_bf16((a),(b),(c),0,0,0)
#define MFMA32(a,b,c) __builtin_amdgcn_mfma_f32_32x32x16_bf16((a),(b),(c),0,0,0)

static __device__ __forceinline__ short f2bf(float f) {
    __hip_bfloat16 h = __float2bfloat16(f);
    return *reinterpret_cast<short*>(&h);
}
static __device__ __forceinline__ float bf2f(short s) {
    unsigned int u = ((unsigned int)(unsigned short)s) << 16;
    return *reinterpret_cast<float*>(&u);
}
static __device__ __forceinline__ unsigned int cvtpk(float a, float b) {
    unsigned int r;
    asm("v_cvt_pk_bf16_f32 %0, %1, %2" : "=v"(r) : "v"(a), "v"(b));
    return r;
}

// folded scale for Q: (1/sqrt(32)) * log2(e)
#define FS 0.2550352584f

// ---- workspace byte offsets -------------------------------------------------
static constexpr size_t OFF_VB   = 0;                        // fp32 V [b,h,n,d]   8 MB
static constexpr size_t OFF_QBF  = 8388608;                  // bf16 Q [b,h,n,d]   4 MB (pre-scaled by FS)
static constexpr size_t OFF_KFR  = 12582912;                 // bf16 kfrag 4 MB
static constexpr size_t OFF_VFR  = 16777216;                 // bf16 vfrag (masked) 4 MB
static constexpr size_t OFF_E1   = 20971520;
static constexpr size_t OFF_E2   = 21004288;
static constexpr size_t OFF_SE1  = 21037056;
static constexpr size_t OFF_SE2  = 21038080;
static constexpr size_t OFF_A2   = 21039104;                 // fp32 [b,h,n,36] 9.4 MB
static constexpr size_t A2S      = 36;
static constexpr size_t OFF_O    = 30476288;                 // bf16 obf (fm) 4 MB; ALIASED xfm
static constexpr size_t OFF_WBF  = 34670592;                 // bf16 wfm [48t][8ks][512] 384 KB
static constexpr size_t OFF_WPBF = 35063808;                 // bf16 wpfm [16t][8ks][512] 128 KB
static constexpr size_t OFF_MR   = 35194880;                 // bf16 maskr [b][32mt][2hi][16] 32 KB
// end = 35,227,648 bytes

// ---------------------------------------------------------------------------
// Kernel 0 (fused): blocks 0..255 weight cvt -> fragment-major bf16;
// blocks 256..263 positional tables; blocks 264..775 x-transpose -> xfm;
// blocks 776..777 maskr: maskr[b][mt][hi][i] = mask[b][mt*32+crow(i,hi)],
// crow(i,hi) = (i&3) + 8*(i>>2) + 4*hi (S^T C/D row order).
// ---------------------------------------------------------------------------
__global__ __launch_bounds__(256) void k_prep(
    const float* __restrict__ Wqk, const float* __restrict__ Wv,
    const float* __restrict__ Wp, const float* __restrict__ mask,
    const float* __restrict__ Wpos, const float* __restrict__ bpos,
    const float* __restrict__ x,
    __hip_bfloat16* __restrict__ wfm, __hip_bfloat16* __restrict__ wpfm,
    __hip_bfloat16* __restrict__ maskr, __hip_bfloat16* __restrict__ xfm,
    float* __restrict__ e1, float* __restrict__ e2,
    float* __restrict__ se1, float* __restrict__ se2)
{
    const int bx = blockIdx.x;
    const int tid = threadIdx.x;
    __shared__ float ps[2][32][8];
    __shared__ float tile[64][68];
    if (bx < 256) {
        int idx = bx * 256 + tid;
        int row = idx >> 6;
        int c4  = (idx & 63) * 4;
        const float* src = (row < 512) ? (Wqk + (size_t)row*256)
                         : (row < 768) ? (Wv + (size_t)(row-512)*256)
                                       : (Wp + (size_t)(row-768)*256);
        float4 v = *(const float4*)(src + c4);
        bf16x4 pk;
        pk[0] = f2bf(v.x); pk[1] = f2bf(v.y); pk[2] = f2bf(v.z); pk[3] = f2bf(v.w);
        int r2 = (row < 768) ? row : (row - 768);
        __hip_bfloat16* dst = (row < 768) ? wfm : wpfm;
        size_t addr = (size_t)(r2 >> 4)*4096 + (size_t)(c4 >> 5)*512
                    + (size_t)((((c4 >> 3) & 3)*16) + (r2 & 15))*8 + (c4 & 7);
        *(bf16x4*)(dst + addr) = pk;
    } else if (bx < 264) {
        const int h = bx - 256;
        const int i = tid >> 3, j4 = (tid & 7) * 4;
        const float wx = Wpos[h*3+0], wy = Wpos[h*3+1], wd = Wpos[h*3+2], bp = bpos[h];
        float fmx = -1e30f, gmx = -1e30f;
        for (int jp = 0; jp < 32; ++jp) {
            float dx = (float)(jp - i);
            float q2 = wd*dx*dx;
            fmx = fmaxf(fmx, wx*dx + q2 + bp);
            gmx = fmaxf(gmx, wy*dx + q2);
        }
        float s1 = 0.f, s2 = 0.f;
        #pragma unroll
        for (int jj = 0; jj < 4; ++jj) {
            int j = j4 + jj;
            float dx = (float)(j - i);
            float q2 = wd*dx*dx;
            float fv = __expf(wx*dx + q2 + bp - fmx);
            float gv = __expf(wy*dx + q2 - gmx);
            e1[h*1024 + i*32 + j] = fv;
            e2[h*1024 + i*32 + j] = gv;
            s1 += fv; s2 += gv;
        }
        ps[0][i][tid & 7] = s1;
        ps[1][i][tid & 7] = s2;
        __syncthreads();
        if (tid < 32) {
            float a = 0.f, c = 0.f;
            #pragma unroll
            for (int k = 0; k < 8; ++k) { a += ps[0][tid][k]; c += ps[1][tid][k]; }
            se1[h*32 + tid] = a;
            se2[h*32 + tid] = c;
        }
    } else if (bx < 776) {
        // x-transpose tile: (B,C,N) fp32 -> xfm fragment-major bf16
        const int bx2 = bx - 264;                 // 0..511
        const int n0 = (bx2 & 15) * 64, c0 = ((bx2 >> 4) & 3) * 64, b = bx2 >> 6;
        {
            int cl = tid >> 2, nq = (tid & 3) * 16;
            const float* src = x + ((size_t)b*C_ + c0 + cl)*N_ + n0 + nq;
            #pragma unroll
            for (int i = 0; i < 4; ++i)
                *(float4*)&tile[cl][nq + i*4] = ((const float4*)src)[i];
        }
        __syncthreads();
        {
            int nl = tid >> 2, cq = (tid & 3) * 16;
            short pk[16];
            #pragma unroll
            for (int i = 0; i < 16; ++i) pk[i] = f2bf(tile[cq + i][nl]);
            int cg = c0 + cq;
            int ks = cg >> 5, g0 = (cg >> 3) & 3;
            size_t base = ((size_t)b*64 + (n0 >> 4) + (nl >> 4))*4096
                        + (size_t)ks*512 + (size_t)(g0*16 + (nl & 15))*8;
            *(uint4*)(xfm + base)       = *(uint4*)&pk[0];
            *(uint4*)(xfm + base + 128) = *(uint4*)&pk[8];
        }
    } else {
        int idx = (bx - 776) * 256 + tid;        // one thread per (b,mt,hi), 512 total
        if (idx < 512) {
            int b = idx >> 6, mt = (idx >> 1) & 31, hi = idx & 1;
            const float* mp = mask + (size_t)b*N_ + mt*32 + 4*hi;
            bf16x8 v0, v1;
            #pragma unroll
            for (int i = 0; i < 8; ++i) v0[i] = f2bf(mp[(i&3) + 8*(i>>2)]);
            #pragma unroll
            for (int i = 0; i < 8; ++i) { int r = i + 8; v1[i] = f2bf(mp[(r&3) + 8*(r>>2)]); }
            *(bf16x8*)(maskr + (size_t)idx*16)     = v0;
            *(bf16x8*)(maskr + (size_t)idx*16 + 8) = v1;
        }
    }
}

// ---------------------------------------------------------------------------
// Kernel 1: QKV projection on MFMA.  A (wfm) and B (xfm) both fragment-major.
// ---------------------------------------------------------------------------
__global__ __launch_bounds__(256) void k_qkv_mfma(
    const __hip_bfloat16* __restrict__ xfm, const __hip_bfloat16* __restrict__ wfm,
    const float* __restrict__ mask,
    __hip_bfloat16* __restrict__ qbf, __hip_bfloat16* __restrict__ kfrag,
    __hip_bfloat16* __restrict__ vfrag, float* __restrict__ vbuf)
{
    const int t = threadIdx.x, w = t >> 6, L = t & 63, lo = L & 15, g = L >> 4;
    const int jw = blockIdx.x * 64 + w * 16;
    const int n0 = blockIdx.y * 64, b = blockIdx.z;

    const __hip_bfloat16* afm = wfm + (size_t)(jw >> 4)*4096 + (size_t)L*8;
    bf16x8 af[8];
    #pragma unroll
    for (int ks = 0; ks < 8; ++ks) af[ks] = *(const bf16x8*)(afm + ks*512);

    const f32x4 Z = {0.f,0.f,0.f,0.f};
    f32x4 D0 = Z, D1 = Z, D2 = Z, D3 = Z;
    const __hip_bfloat16* xb = xfm + ((size_t)b*64 + (n0 >> 4))*4096 + (size_t)L*8;
    #pragma unroll
    for (int ks = 0; ks < 8; ++ks) {
        bf16x8 b0 = *(const bf16x8*)(xb + ks*512);
        bf16x8 b1 = *(const bf16x8*)(xb + 4096 + ks*512);
        bf16x8 b2 = *(const bf16x8*)(xb + 8192 + ks*512);
        bf16x8 b3 = *(const bf16x8*)(xb + 12288 + ks*512);
        D0 = MFMA16(af[ks], b0, D0);
        D1 = MFMA16(af[ks], b1, D1);
        D2 = MFMA16(af[ks], b2, D2);
        D3 = MFMA16(af[ks], b3, D3);
    }
    f32x4 D[4] = {D0, D1, D2, D3};

    const size_t bb = (size_t)b*NH_;
    if (jw < 256) {                       // Q: row-major, pre-scaled by FS
        int h = jw >> 5, d0 = (jw & 31) + 4*g;
        #pragma unroll
        for (int nt = 0; nt < 4; ++nt) {
            int nn = n0 + nt*16 + lo;
            bf16x4 pk;
            #pragma unroll
            for (int r = 0; r < 4; ++r) pk[r] = f2bf(D[nt][r] * FS);
            *(bf16x4*)(qbf + ((bb + h)*N_ + nn)*HD_ + d0) = pk;
        }
    } else if (jw < 512) {                // K -> fragment-major kfrag
        int j2 = jw & 255, h = j2 >> 5, d0 = (j2 & 31) + 4*g;
        size_t base = (bb + h)*32768 + (size_t)(d0 >> 4)*512
                    + (size_t)((d0 >> 3) & 1)*256 + (d0 & 7);
        #pragma unroll
        for (int nt = 0; nt < 4; ++nt) {
            int nn = n0 + nt*16 + lo;
            bf16x4 pk;
            #pragma unroll
            for (int r = 0; r < 4; ++r) pk[r] = f2bf(D[nt][r]);
            *(bf16x4*)(kfrag + base + (size_t)(nn >> 5)*1024 + (nn & 31)*8) = pk;
        }
    } else {                              // V -> fp32 vbuf + masked vfrag
        int j2 = jw - 512, h = j2 >> 5, d0 = (j2 & 31) + 4*g;
        #pragma unroll
        for (int nt = 0; nt < 4; ++nt) {
            int nn = n0 + nt*16 + lo;
            float mval = mask[(size_t)b*N_ + nn];
            float4 fv = make_float4(D[nt][0], D[nt][1], D[nt][2], D[nt][3]);
            *(float4*)(vbuf + ((bb + h)*N_ + nn)*HD_ + d0) = fv;
            size_t vbase = (bb + h)*32768 + (size_t)(nn >> 5)*1024
                         + (size_t)((nn >> 4) & 1)*512 + (size_t)((nn >> 3) & 1)*256
                         + (nn & 7);
            #pragma unroll
            for (int r = 0; r < 4; ++r)
                vfrag[vbase + (size_t)(d0 + r)*8] = __float2bfloat16(D[nt][r] * mval);
        }
    }
}

// ---------------------------------------------------------------------------
// Kernel 3: positional attention @ V, fused two-phase per block.
// ---------------------------------------------------------------------------
__global__ __launch_bounds__(256) void k_pos_apply(
    const float* __restrict__ vb, const float* __restrict__ mask,
    const float* __restrict__ e1, const float* __restrict__ e2,
    float* __restrict__ a2)
{
    const int rn = blockIdx.x, h = blockIdx.y, b = blockIdx.z;
    const int tid = threadIdx.x;
    const int cm = tid >> 3, dq = tid & 7;
    __shared__ float t1[32][36];
    __shared__ float e1s[32][36];
    __shared__ float t1m[32];
    __shared__ float e2s[32];
    const float* vbh = vb + (((size_t)b*NH_ + h)*N_)*HD_;
    const float* mb  = mask + (size_t)b*N_;

    {
        int r = tid >> 3, c4 = (tid & 7) * 4;
        *(float4*)&e1s[r][c4] = *(const float4*)(e1 + h*1024 + r*32 + c4);
        if (tid < 32) e2s[tid] = e2[h*1024 + rn*32 + tid];
    }
    __syncthreads();

    {
        float4 acc = make_float4(0.f,0.f,0.f,0.f);
        const float* vcol = vbh + cm*HD_ + dq*4;
        #pragma unroll 8
        for (int rm = 0; rm < 32; ++rm) {
            float4 vv = *(const float4*)(vcol + (size_t)rm*32*HD_);
            float wgt = e2s[rm];
            acc.x = fmaf(wgt, vv.x, acc.x);
            acc.y = fmaf(wgt, vv.y, acc.y);
            acc.z = fmaf(wgt, vv.z, acc.z);
            acc.w = fmaf(wgt, vv.w, acc.w);
        }
        *(float4*)&t1[cm][dq*4] = acc;
    }
    if (tid < 32) {
        float s = 0.f;
        for (int rm = 0; rm < 32; ++rm)
            s = fmaf(e2s[rm], mb[rm*32 + tid], s);
        t1m[tid] = s;
    }
    __syncthreads();

    const size_t bh = (size_t)b*NH_ + h;
    {
        const int cn = cm;
        float4 acc = make_float4(0.f,0.f,0.f,0.f);
        #pragma unroll 8
        for (int ci = 0; ci < 32; ++ci) {
            float wgt = e1s[cn][ci];
            float4 tv = *(const float4*)&t1[ci][dq*4];
            acc.x = fmaf(wgt, tv.x, acc.x);
            acc.y = fmaf(wgt, tv.y, acc.y);
            acc.z = fmaf(wgt, tv.z, acc.z);
            acc.w = fmaf(wgt, tv.w, acc.w);
        }
        int n = rn*32 + cn;
        *(float4*)(a2 + (bh*N_ + n)*A2S + dq*4) = acc;
    }
    if (tid < 32) {
        float s = 0.f;
        for (int ci = 0; ci < 32; ++ci)
            s = fmaf(e1s[tid][ci], t1m[ci], s);
        a2[(bh*N_ + rn*32 + tid)*A2S + 32] = s;
    }
}

// ---------------------------------------------------------------------------
// Kernel 4: attention.  R9/R13 structure (4 n-subtiles x 2 m-halves, XCD
// swizzle, fm loads) with (a) zs/z1m on the VALU via crow-ordered maskr
// (no Z-MFMAs, no zfrag; scheme validated in R10) and (b) 2-deep prefetch
// (unroll-2, two buffer sets) so each K/V load has ~2 iterations to land.
// ---------------------------------------------------------------------------
__global__ __launch_bounds__(512, 4) void k_attn_mfma(
    const __hip_bfloat16* __restrict__ qbf, const __hip_bfloat16* __restrict__ kfrag,
    const __hip_bfloat16* __restrict__ vfrag, const __hip_bfloat16* __restrict__ maskr,
    const float* __restrict__ a2, const float* __restrict__ se1,
    const float* __restrict__ se2, const float* __restrict__ gating,
    __hip_bfloat16* __restrict__ ob)
{
    const int bid = blockIdx.x;
    const int swz = ((bid & 7) << 6) | (bid >> 3);   // bijective (512 = 8*64)
    const int xt = swz & 7, h = (swz >> 3) & 7, b = swz >> 6;

    const int t = threadIdx.x, w = t >> 6, L = t & 63;
    const int ln = L & 31, hi = L >> 5;
    const int nh = w & 3, sp = w >> 2;           // n-subtile (4), m-half (2)
    const int n0 = xt * 128 + nh * 32;
    const size_t bh = (size_t)b*NH_ + h;
    const __hip_bfloat16* qh = qbf + bh*(size_t)N_*HD_;
    const size_t spo = (size_t)sp * 16 * 1024;   // m-half offset (16 tiles)
    const __hip_bfloat16* kf = kfrag + bh*32768 + spo + (size_t)L*8;
    const __hip_bfloat16* vf = vfrag + bh*32768 + spo + (size_t)L*8;
    const __hip_bfloat16* mrp = maskr + ((size_t)(b*32 + sp*16)*2 + hi)*16;

    __shared__ float ldsO[128*32];               // [n_local][d]  16 KB
    __shared__ float ldsZ[128*2];                // [n_local][{zs,z1}]

    bf16x8 qf0 = *(const bf16x8*)(qh + (size_t)(n0 + ln)*HD_ + 8*hi);
    bf16x8 qf1 = *(const bf16x8*)(qh + (size_t)(n0 + ln)*HD_ + 16 + 8*hi);

    f32x16 O;
    #pragma unroll
    for (int i = 0; i < 16; ++i) O[i] = 0.f;
    float zs = 0.f, z1 = 0.f;

    // two buffer sets: A = even tiles, B = odd tiles (2-deep prefetch)
    bf16x8 ak0 = *(const bf16x8*)(kf);
    bf16x8 ak1 = *(const bf16x8*)(kf + 512);
    bf16x8 av0 = *(const bf16x8*)(vf);
    bf16x8 av1 = *(const bf16x8*)(vf + 512);
    bf16x8 bk0 = *(const bf16x8*)(kf + 1024);
    bf16x8 bk1 = *(const bf16x8*)(kf + 1024 + 512);
    bf16x8 bv0 = *(const bf16x8*)(vf + 1024);
    bf16x8 bv1 = *(const bf16x8*)(vf + 1024 + 512);

#define ATTN_STEP(K0,K1,V0,V1,MT_) do {                                        \
    f32x16 S;                                                                  \
    _Pragma("unroll")                                                          \
    for (int i = 0; i < 16; ++i) S[i] = 0.f;                                   \
    S = MFMA32(K0, qf0, S);                                                    \
    S = MFMA32(K1, qf1, S);                                                    \
    const int mtpf = ((MT_) + 2 < 16) ? (MT_) + 2 : 15;                        \
    const size_t opf = (size_t)mtpf * 1024;                                    \
    bf16x8 nk0 = *(const bf16x8*)(kf + opf);                                   \
    bf16x8 nk1 = *(const bf16x8*)(kf + opf + 512);                             \
    bf16x8 nv0 = *(const bf16x8*)(vf + opf);                                   \
    bf16x8 nv1 = *(const bf16x8*)(vf + opf + 512);                             \
    bf16x8 mr0 = *(const bf16x8*)(mrp + (MT_)*32);                             \
    bf16x8 mr1 = *(const bf16x8*)(mrp + (MT_)*32 + 8);                         \
    float e[16];                                                               \
    _Pragma("unroll")                                                          \
    for (int i = 0; i < 16; ++i) e[i] = exp2f(S[i]);                           \
    _Pragma("unroll")                                                          \
    for (int j = 0; j < 8; ++j) {                                              \
        zs += e[j] + e[8+j];                                                   \
        z1 = fmaf(e[j], bf2f(mr0[j]), fmaf(e[8+j], bf2f(mr1[j]), z1));         \
    }                                                                          \
    unsigned int x01 = cvtpk(e[0], e[1]), x23 = cvtpk(e[2], e[3]);             \
    unsigned int x45 = cvtpk(e[4], e[5]), x67 = cvtpk(e[6], e[7]);             \
    u32x2 r02 = __builtin_amdgcn_permlane32_swap(x01, x45, false, false);      \
    u32x2 r13 = __builtin_amdgcn_permlane32_swap(x23, x67, false, false);      \
    u32x4 p0u = { r02[0], r13[0], r02[1], r13[1] };                            \
    bf16x8 pa0 = *reinterpret_cast<bf16x8*>(&p0u);                             \
    unsigned int y01 = cvtpk(e[8], e[9]),  y23 = cvtpk(e[10], e[11]);          \
    unsigned int y45 = cvtpk(e[12], e[13]), y67 = cvtpk(e[14], e[15]);         \
    u32x2 s02 = __builtin_amdgcn_permlane32_swap(y01, y45, false, false);      \
    u32x2 s13 = __builtin_amdgcn_permlane32_swap(y23, y67, false, false);      \
    u32x4 p1u = { s02[0], s13[0], s02[1], s13[1] };                            \
    bf16x8 pa1 = *reinterpret_cast<bf16x8*>(&p1u);                             \
    O = MFMA32(pa0, V0, O);                                                    \
    O = MFMA32(pa1, V1, O);                                                    \
    K0 = nk0; K1 = nk1; V0 = nv0; V1 = nv1;                                    \
} while (0)

    for (int mt = 0; mt < 16; mt += 2) {
        ATTN_STEP(ak0, ak1, av0, av1, mt);       // consume A, prefetch A <- mt+2
        ATTN_STEP(bk0, bk1, bv0, bv1, mt + 1);   // consume B, prefetch B <- mt+3
    }
#undef ATTN_STEP

    // combine hi-halves of lane-local z sums (disjoint m coverage)
    zs += __shfl_xor(zs, 32);
    z1 += __shfl_xor(z1, 32);

    // ---- combine the 2 m-halves via LDS ----
    if (sp == 1) {
        #pragma unroll
        for (int r = 0; r < 16; ++r) {
            int nl = nh*32 + (r&3) + 8*(r>>2) + 4*hi;
            ldsO[nl*32 + ln] = O[r];
        }
        if (L < 32) {
            ldsZ[(nh*32 + ln)*2 + 0] = zs;
            ldsZ[(nh*32 + ln)*2 + 1] = z1;
        }
    }
    __syncthreads();
    if (sp == 0) {
        #pragma unroll
        for (int r = 0; r < 16; ++r) {
            int nl = nh*32 + (r&3) + 8*(r>>2) + 4*hi;
            O[r] += ldsO[nl*32 + ln];
        }
        if (L < 32) {
            zs += ldsZ[(nh*32 + ln)*2 + 0];
            z1 += ldsZ[(nh*32 + ln)*2 + 1];
        }

        const float gs = 1.f / (1.f + __expf(-gating[h]));
        #pragma unroll
        for (int r = 0; r < 16; ++r) {
            const int crow = (r&3) + 8*(r>>2) + 4*hi;
            const int n = n0 + crow;
            float zsv = __shfl(zs, crow);
            float z1v = __shfl(z1, crow);
            const float* a2p = a2 + (bh*N_ + n)*A2S;
            float z2m = a2p[32];
            float zp  = se1[h*32 + (n & 31)] * se2[h*32 + (n >> 5)];
            float w1  = (1.f - gs) / zsv;
            float w2  = gs / zp;
            float inv = 1.f / (w1*z1v + w2*z2m);
            float o = (w1*O[r] + w2*a2p[ln]) * inv;
            // fragment-major obf write: element (n, c=h*32+ln)
            size_t oaddr = ((size_t)b*64 + (n >> 4))*4096 + (size_t)h*512
                         + (size_t)((ln >> 3)*16 + (n & 15))*8 + (ln & 7);
            ob[oaddr] = __float2bfloat16(o);
        }
    }
}

// ---------------------------------------------------------------------------
// Kernel 5: output projection on MFMA.  A (wpfm) and B (obf) both
// fragment-major -> all loads coalesced 1KB instructions.
// ---------------------------------------------------------------------------
__global__ __launch_bounds__(256) void k_proj_mfma(
    const __hip_bfloat16* __restrict__ obf, const __hip_bfloat16* __restrict__ wpfm,
    const float* __restrict__ bp, float* __restrict__ out)
{
    const int t = threadIdx.x, w = t >> 6, L = t & 63, lo = L & 15, g = L >> 4;
    const int cw = blockIdx.x * 64 + w * 16;
    const int n0 = blockIdx.y * 64, b = blockIdx.z;

    const __hip_bfloat16* afm = wpfm + (size_t)(cw >> 4)*4096 + (size_t)L*8;
    bf16x8 af[8];
    #pragma unroll
    for (int ks = 0; ks < 8; ++ks) af[ks] = *(const bf16x8*)(afm + ks*512);

    const f32x4 Z = {0.f,0.f,0.f,0.f};
    f32x4 D0 = Z, D1 = Z, D2 = Z, D3 = Z;
    const __hip_bfloat16* xb = obf + ((size_t)b*64 + (n0 >> 4))*4096 + (size_t)L*8;
    #pragma unroll
    for (int ks = 0; ks < 8; ++ks) {
        bf16x8 b0 = *(const bf16x8*)(xb + ks*512);
        bf16x8 b1 = *(const bf16x8*)(xb + 4096 + ks*512);
        bf16x8 b2 = *(const bf16x8*)(xb + 8192 + ks*512);
        bf16x8 b3 = *(const bf16x8*)(xb + 12288 + ks*512);
        D0 = MFMA16(af[ks], b0, D0);
        D1 = MFMA16(af[ks], b1, D1);
        D2 = MFMA16(af[ks], b2, D2);
        D3 = MFMA16(af[ks], b3, D3);
    }
    f32x4 D[4] = {D0, D1, D2, D3};

    float bias[4];
    #pragma unroll
    for (int r = 0; r < 4; ++r) bias[r] = bp[cw + 4*g + r];
    #pragma unroll
    for (int nt = 0; nt < 4; ++nt) {
        int nn = n0 + nt*16 + lo;
        #pragma unroll
        for (int r = 0; r < 4; ++r)
            out[((size_t)b*C_ + cw + 4*g + r)*N_ + nn] = D[nt][r] + bias[r];
    }
}

// ---------------------------------------------------------------------------
extern "C" void kernel_launch(void* const* d_in, const int* in_sizes, int n_in,
                              void* d_out, int out_size, void* d_ws, size_t ws_size,
                              hipStream_t stream)
{
    (void)in_sizes; (void)n_in; (void)out_size; (void)ws_size;
    const float* x      = (const float*)d_in[0];
    const float* mask   = (const float*)d_in[1];
    const float* Wqk    = (const float*)d_in[2];
    const float* Wv     = (const float*)d_in[3];
    const float* Wproj  = (const float*)d_in[4];
    const float* bproj  = (const float*)d_in[5];
    const float* Wpos   = (const float*)d_in[6];
    const float* bpos   = (const float*)d_in[7];
    const float* gating = (const float*)d_in[8];
    float* out = (float*)d_out;
    char* w = (char*)d_ws;

    float*          vbuf  = (float*)(w + OFF_VB);
    __hip_bfloat16* qbf   = (__hip_bfloat16*)(w + OFF_QBF);
    __hip_bfloat16* kfrag = (__hip_bfloat16*)(w + OFF_KFR);
    __hip_bfloat16* vfrag = (__hip_bfloat16*)(w + OFF_VFR);
    float*          e1    = (float*)(w + OFF_E1);
    float*          e2    = (float*)(w + OFF_E2);
    float*          se1   = (float*)(w + OFF_SE1);
    float*          se2   = (float*)(w + OFF_SE2);
    float*          a2    = (float*)(w + OFF_A2);
    __hip_bfloat16* obf   = (__hip_bfloat16*)(w + OFF_O);
    __hip_bfloat16* xfm   = (__hip_bfloat16*)(w + OFF_O);   // alias: lifetime disjoint
    __hip_bfloat16* wfm   = (__hip_bfloat16*)(w + OFF_WBF);
    __hip_bfloat16* wpfm  = (__hip_bfloat16*)(w + OFF_WPBF);
    __hip_bfloat16* maskr = (__hip_bfloat16*)(w + OFF_MR);

    k_prep<<<dim3(778), dim3(256), 0, stream>>>(Wqk, Wv, Wproj, mask, Wpos, bpos, x,
                                                wfm, wpfm, maskr, xfm, e1, e2, se1, se2);
    k_qkv_mfma<<<dim3(12,16,8), dim3(256), 0, stream>>>(xfm, wfm, mask, qbf, kfrag, vfrag, vbuf);
    k_pos_apply<<<dim3(32,8,8), dim3(256), 0, stream>>>(vbuf, mask, e1, e2, a2);
    k_attn_mfma<<<dim3(512), dim3(512), 0, stream>>>(qbf, kfrag, vfrag, maskr, a2, se1, se2, gating, obf);
    k_proj_mfma<<<dim3(4,16,8), dim3(256), 0, stream>>>(obf, wpfm, bproj, out);
}

// Round 15
// 75.992 us; speedup vs baseline: 1.0395x; 1.0395x over previous
//
#include <hip/hip_runtime.h>
#include <hip/hip_bf16.h>
#include <math.h>

#define B_ 8
#define C_ 256
#define N_ 1024
#define NH_ 8
#define HD_ 32

typedef __attribute__((ext_vector_type(8))) short bf16x8;
typedef __attribute__((ext_vector_type(4))) short bf16x4;
typedef __attribute__((ext_vector_type(4))) float f32x4;
typedef __attribute__((ext_vector_type(16))) float f32x16;
typedef __attribute__((ext_vector_type(2))) unsigned int u32x2;
typedef __attribute__((ext_vector_type(4))) unsigned int u32x4;
#define MFMA16(a,b,c) __builtin_amdgcn_mfma_f32_16x16x32_bf16((a),(b),(c),0,0,0)
#define MFMA32(a,b,c) __builtin_amdgcn_mfma_f32_32x32x16_bf16((a),(b),(c),0,0,0)

static __device__ __forceinline__ short f2bf(float f) {
    __hip_bfloat16 h = __float2bfloat16(f);
    return *reinterpret_cast<short*>(&h);
}
static __device__ __forceinline__ unsigned int cvtpk(float a, float b) {
    unsigned int r;
    asm("v_cvt_pk_bf16_f32 %0, %1, %2" : "=v"(r) : "v"(a), "v"(b));
    return r;
}

// folded scale for Q: (1/sqrt(32)) * log2(e)
#define FS 0.2550352584f

// ---- workspace byte offsets -------------------------------------------------
// Fragment-major (fm) layouts:
//  * K/V per (b,h), per 32-m tile (2048 B): lane L's 16 B at tile+L*16 / +1024.
//  * W / x / obf as [tile of 16 rows][ks=k/32][slot=((k>>3)&3)*16 + (r&15)]:
//    element (r,k) at tile(r>>4)*4096 + (k>>5)*512 + slot*8 + (k&7).
static constexpr size_t OFF_VB   = 0;                        // fp32 V [b,h,n,d]   8 MB
static constexpr size_t OFF_QBF  = 8388608;                  // bf16 Q [b,h,n,d]   4 MB (pre-scaled by FS)
static constexpr size_t OFF_KFR  = 12582912;                 // bf16 kfrag 4 MB
static constexpr size_t OFF_VFR  = 16777216;                 // bf16 vfrag (masked) 4 MB
static constexpr size_t OFF_E1   = 20971520;
static constexpr size_t OFF_E2   = 21004288;
static constexpr size_t OFF_SE1  = 21037056;
static constexpr size_t OFF_SE2  = 21038080;
static constexpr size_t OFF_A2   = 21039104;                 // fp32 [b,h,n,36] 9.4 MB
static constexpr size_t A2S      = 36;
static constexpr size_t OFF_O    = 30476288;                 // bf16 obf (fm) 4 MB; ALIASED xfm
static constexpr size_t OFF_WBF  = 34670592;                 // bf16 wfm [48t][8ks][512] 384 KB
static constexpr size_t OFF_WPBF = 35063808;                 // bf16 wpfm [16t][8ks][512] 128 KB
static constexpr size_t OFF_ZFR  = 35194880;                 // bf16 zfrag [b][32mt][1024] 512 KB
// end = 35,719,168 bytes

// ---------------------------------------------------------------------------
// Kernel 0 (fused): blocks 0..255 weight cvt -> fragment-major bf16;
// blocks 256..383 zfrag; blocks 384..391 positional tables;
// blocks 392..903 x-transpose -> xfm (fragment-major bf16).
// ---------------------------------------------------------------------------
__global__ __launch_bounds__(256) void k_prep(
    const float* __restrict__ Wqk, const float* __restrict__ Wv,
    const float* __restrict__ Wp, const float* __restrict__ mask,
    const float* __restrict__ Wpos, const float* __restrict__ bpos,
    const float* __restrict__ x,
    __hip_bfloat16* __restrict__ wfm, __hip_bfloat16* __restrict__ wpfm,
    __hip_bfloat16* __restrict__ zfrag, __hip_bfloat16* __restrict__ xfm,
    float* __restrict__ e1, float* __restrict__ e2,
    float* __restrict__ se1, float* __restrict__ se2)
{
    const int bx = blockIdx.x;
    const int tid = threadIdx.x;
    __shared__ float ps[2][32][8];
    __shared__ float tile[64][68];
    if (bx < 256) {
        int idx = bx * 256 + tid;
        int row = idx >> 6;
        int c4  = (idx & 63) * 4;
        const float* src = (row < 512) ? (Wqk + (size_t)row*256)
                         : (row < 768) ? (Wv + (size_t)(row-512)*256)
                                       : (Wp + (size_t)(row-768)*256);
        float4 v = *(const float4*)(src + c4);
        bf16x4 pk;
        pk[0] = f2bf(v.x); pk[1] = f2bf(v.y); pk[2] = f2bf(v.z); pk[3] = f2bf(v.w);
        int r2 = (row < 768) ? row : (row - 768);
        __hip_bfloat16* dst = (row < 768) ? wfm : wpfm;
        size_t addr = (size_t)(r2 >> 4)*4096 + (size_t)(c4 >> 5)*512
                    + (size_t)((((c4 >> 3) & 3)*16) + (r2 & 15))*8 + (c4 & 7);
        *(bf16x4*)(dst + addr) = pk;
    } else if (bx < 384) {
        int idx = (bx - 256) * 256 + tid;       // 32768 threads, 16B each
        int L8  = idx & 127;
        int mt  = (idx >> 7) & 31;
        int b   = idx >> 12;
        int region = L8 >> 6;
        int slot   = L8 & 63;
        int zrow = slot & 31, shi = slot >> 5;
        bf16x8 v;
        if (zrow == 0) {
            int m = mt*32 + region*16 + shi*8;
            const float* mp = mask + (size_t)b*N_ + m;
            #pragma unroll
            for (int j = 0; j < 8; ++j) v[j] = f2bf(mp[j]);
        } else {
            short c = (zrow == 1) ? (short)0x3F80 : (short)0;
            #pragma unroll
            for (int j = 0; j < 8; ++j) v[j] = c;
        }
        *(bf16x8*)(zfrag + ((size_t)b*32 + mt)*1024 + region*512 + slot*8) = v;
    } else if (bx < 392) {
        const int h = bx - 384;
        const int i = tid >> 3, j4 = (tid & 7) * 4;
        const float wx = Wpos[h*3+0], wy = Wpos[h*3+1], wd = Wpos[h*3+2], bp = bpos[h];
        float fmx = -1e30f, gmx = -1e30f;
        for (int jp = 0; jp < 32; ++jp) {
            float dx = (float)(jp - i);
            float q2 = wd*dx*dx;
            fmx = fmaxf(fmx, wx*dx + q2 + bp);
            gmx = fmaxf(gmx, wy*dx + q2);
        }
        float s1 = 0.f, s2 = 0.f;
        #pragma unroll
        for (int jj = 0; jj < 4; ++jj) {
            int j = j4 + jj;
            float dx = (float)(j - i);
            float q2 = wd*dx*dx;
            float fv = __expf(wx*dx + q2 + bp - fmx);
            float gv = __expf(wy*dx + q2 - gmx);
            e1[h*1024 + i*32 + j] = fv;
            e2[h*1024 + i*32 + j] = gv;
            s1 += fv; s2 += gv;
        }
        ps[0][i][tid & 7] = s1;
        ps[1][i][tid & 7] = s2;
        __syncthreads();
        if (tid < 32) {
            float a = 0.f, c = 0.f;
            #pragma unroll
            for (int k = 0; k < 8; ++k) { a += ps[0][tid][k]; c += ps[1][tid][k]; }
            se1[h*32 + tid] = a;
            se2[h*32 + tid] = c;
        }
    } else {
        // x-transpose tile: (B,C,N) fp32 -> xfm fragment-major bf16
        const int bx2 = bx - 392;                 // 0..511
        const int n0 = (bx2 & 15) * 64, c0 = ((bx2 >> 4) & 3) * 64, b = bx2 >> 6;
        {
            int cl = tid >> 2, nq = (tid & 3) * 16;
            const float* src = x + ((size_t)b*C_ + c0 + cl)*N_ + n0 + nq;
            #pragma unroll
            for (int i = 0; i < 4; ++i)
                *(float4*)&tile[cl][nq + i*4] = ((const float4*)src)[i];
        }
        __syncthreads();
        {
            int nl = tid >> 2, cq = (tid & 3) * 16;
            short pk[16];
            #pragma unroll
            for (int i = 0; i < 16; ++i) pk[i] = f2bf(tile[cq + i][nl]);
            int cg = c0 + cq;
            int ks = cg >> 5, g0 = (cg >> 3) & 3;
            size_t base = ((size_t)b*64 + (n0 >> 4) + (nl >> 4))*4096
                        + (size_t)ks*512 + (size_t)(g0*16 + (nl & 15))*8;
            *(uint4*)(xfm + base)       = *(uint4*)&pk[0];
            *(uint4*)(xfm + base + 128) = *(uint4*)&pk[8];
        }
    }
}

// ---------------------------------------------------------------------------
// Kernel 1: QKV projection on MFMA.  A (wfm) and B (xfm) both fragment-major.
// ---------------------------------------------------------------------------
__global__ __launch_bounds__(256) void k_qkv_mfma(
    const __hip_bfloat16* __restrict__ xfm, const __hip_bfloat16* __restrict__ wfm,
    const float* __restrict__ mask,
    __hip_bfloat16* __restrict__ qbf, __hip_bfloat16* __restrict__ kfrag,
    __hip_bfloat16* __restrict__ vfrag, float* __restrict__ vbuf)
{
    const int t = threadIdx.x, w = t >> 6, L = t & 63, lo = L & 15, g = L >> 4;
    const int jw = blockIdx.x * 64 + w * 16;
    const int n0 = blockIdx.y * 64, b = blockIdx.z;

    const __hip_bfloat16* afm = wfm + (size_t)(jw >> 4)*4096 + (size_t)L*8;
    bf16x8 af[8];
    #pragma unroll
    for (int ks = 0; ks < 8; ++ks) af[ks] = *(const bf16x8*)(afm + ks*512);

    const f32x4 Z = {0.f,0.f,0.f,0.f};
    f32x4 D0 = Z, D1 = Z, D2 = Z, D3 = Z;
    const __hip_bfloat16* xb = xfm + ((size_t)b*64 + (n0 >> 4))*4096 + (size_t)L*8;
    #pragma unroll
    for (int ks = 0; ks < 8; ++ks) {
        bf16x8 b0 = *(const bf16x8*)(xb + ks*512);
        bf16x8 b1 = *(const bf16x8*)(xb + 4096 + ks*512);
        bf16x8 b2 = *(const bf16x8*)(xb + 8192 + ks*512);
        bf16x8 b3 = *(const bf16x8*)(xb + 12288 + ks*512);
        D0 = MFMA16(af[ks], b0, D0);
        D1 = MFMA16(af[ks], b1, D1);
        D2 = MFMA16(af[ks], b2, D2);
        D3 = MFMA16(af[ks], b3, D3);
    }
    f32x4 D[4] = {D0, D1, D2, D3};

    const size_t bb = (size_t)b*NH_;
    if (jw < 256) {                       // Q: row-major, pre-scaled by FS
        int h = jw >> 5, d0 = (jw & 31) + 4*g;
        #pragma unroll
        for (int nt = 0; nt < 4; ++nt) {
            int nn = n0 + nt*16 + lo;
            bf16x4 pk;
            #pragma unroll
            for (int r = 0; r < 4; ++r) pk[r] = f2bf(D[nt][r] * FS);
            *(bf16x4*)(qbf + ((bb + h)*N_ + nn)*HD_ + d0) = pk;
        }
    } else if (jw < 512) {                // K -> fragment-major kfrag
        int j2 = jw & 255, h = j2 >> 5, d0 = (j2 & 31) + 4*g;
        size_t base = (bb + h)*32768 + (size_t)(d0 >> 4)*512
                    + (size_t)((d0 >> 3) & 1)*256 + (d0 & 7);
        #pragma unroll
        for (int nt = 0; nt < 4; ++nt) {
            int nn = n0 + nt*16 + lo;
            bf16x4 pk;
            #pragma unroll
            for (int r = 0; r < 4; ++r) pk[r] = f2bf(D[nt][r]);
            *(bf16x4*)(kfrag + base + (size_t)(nn >> 5)*1024 + (nn & 31)*8) = pk;
        }
    } else {                              // V -> fp32 vbuf + masked vfrag
        int j2 = jw - 512, h = j2 >> 5, d0 = (j2 & 31) + 4*g;
        #pragma unroll
        for (int nt = 0; nt < 4; ++nt) {
            int nn = n0 + nt*16 + lo;
            float mval = mask[(size_t)b*N_ + nn];
            float4 fv = make_float4(D[nt][0], D[nt][1], D[nt][2], D[nt][3]);
            *(float4*)(vbuf + ((bb + h)*N_ + nn)*HD_ + d0) = fv;
            size_t vbase = (bb + h)*32768 + (size_t)(nn >> 5)*1024
                         + (size_t)((nn >> 4) & 1)*512 + (size_t)((nn >> 3) & 1)*256
                         + (nn & 7);
            #pragma unroll
            for (int r = 0; r < 4; ++r)
                vfrag[vbase + (size_t)(d0 + r)*8] = __float2bfloat16(D[nt][r] * mval);
        }
    }
}

// ---------------------------------------------------------------------------
// Kernel 3: positional attention @ V, fused two-phase per block.
// ---------------------------------------------------------------------------
__global__ __launch_bounds__(256) void k_pos_apply(
    const float* __restrict__ vb, const float* __restrict__ mask,
    const float* __restrict__ e1, const float* __restrict__ e2,
    float* __restrict__ a2)
{
    const int rn = blockIdx.x, h = blockIdx.y, b = blockIdx.z;
    const int tid = threadIdx.x;
    const int cm = tid >> 3, dq = tid & 7;
    __shared__ float t1[32][36];
    __shared__ float e1s[32][36];
    __shared__ float t1m[32];
    __shared__ float e2s[32];
    const float* vbh = vb + (((size_t)b*NH_ + h)*N_)*HD_;
    const float* mb  = mask + (size_t)b*N_;

    {
        int r = tid >> 3, c4 = (tid & 7) * 4;
        *(float4*)&e1s[r][c4] = *(const float4*)(e1 + h*1024 + r*32 + c4);
        if (tid < 32) e2s[tid] = e2[h*1024 + rn*32 + tid];
    }
    __syncthreads();

    {
        float4 acc = make_float4(0.f,0.f,0.f,0.f);
        const float* vcol = vbh + cm*HD_ + dq*4;
        #pragma unroll 8
        for (int rm = 0; rm < 32; ++rm) {
            float4 vv = *(const float4*)(vcol + (size_t)rm*32*HD_);
            float wgt = e2s[rm];
            acc.x = fmaf(wgt, vv.x, acc.x);
            acc.y = fmaf(wgt, vv.y, acc.y);
            acc.z = fmaf(wgt, vv.z, acc.z);
            acc.w = fmaf(wgt, vv.w, acc.w);
        }
        *(float4*)&t1[cm][dq*4] = acc;
    }
    if (tid < 32) {
        float s = 0.f;
        for (int rm = 0; rm < 32; ++rm)
            s = fmaf(e2s[rm], mb[rm*32 + tid], s);
        t1m[tid] = s;
    }
    __syncthreads();

    const size_t bh = (size_t)b*NH_ + h;
    {
        const int cn = cm;
        float4 acc = make_float4(0.f,0.f,0.f,0.f);
        #pragma unroll 8
        for (int ci = 0; ci < 32; ++ci) {
            float wgt = e1s[cn][ci];
            float4 tv = *(const float4*)&t1[ci][dq*4];
            acc.x = fmaf(wgt, tv.x, acc.x);
            acc.y = fmaf(wgt, tv.y, acc.y);
            acc.z = fmaf(wgt, tv.z, acc.z);
            acc.w = fmaf(wgt, tv.w, acc.w);
        }
        int n = rn*32 + cn;
        *(float4*)(a2 + (bh*N_ + n)*A2S + dq*4) = acc;
    }
    if (tid < 32) {
        float s = 0.f;
        for (int ci = 0; ci < 32; ++ci)
            s = fmaf(e1s[tid][ci], t1m[ci], s);
        a2[(bh*N_ + rn*32 + tid)*A2S + 32] = s;
    }
}

// ---------------------------------------------------------------------------
// Kernel 4: attention (round-12/13 best-measured core: Z-MFMA, 1-deep
// prefetch, fm loads, XCD swizzle, fm obf write) + T5 s_setprio around
// the MFMA clusters (waves are barrier-free in the loop -> role diversity).
// ---------------------------------------------------------------------------
__global__ __launch_bounds__(512, 4) void k_attn_mfma(
    const __hip_bfloat16* __restrict__ qbf, const __hip_bfloat16* __restrict__ kfrag,
    const __hip_bfloat16* __restrict__ vfrag, const __hip_bfloat16* __restrict__ zfrag,
    const float* __restrict__ a2, const float* __restrict__ se1,
    const float* __restrict__ se2, const float* __restrict__ gating,
    __hip_bfloat16* __restrict__ ob)
{
    const int bid = blockIdx.x;
    const int swz = ((bid & 7) << 6) | (bid >> 3);   // bijective (512 = 8*64)
    const int xt = swz & 7, h = (swz >> 3) & 7, b = swz >> 6;

    const int t = threadIdx.x, w = t >> 6, L = t & 63;
    const int ln = L & 31, hi = L >> 5;
    const int nh = w & 3, sp = w >> 2;           // n-subtile (4), m-half (2)
    const int n0 = xt * 128 + nh * 32;
    const size_t bh = (size_t)b*NH_ + h;
    const __hip_bfloat16* qh = qbf + bh*(size_t)N_*HD_;
    const size_t spo = (size_t)sp * 16 * 1024;   // m-half offset (16 tiles)
    const __hip_bfloat16* kf = kfrag + bh*32768 + spo + (size_t)L*8;
    const __hip_bfloat16* vf = vfrag + bh*32768 + spo + (size_t)L*8;
    const __hip_bfloat16* zf = zfrag + (size_t)b*32768 + spo + (size_t)L*8;

    __shared__ float ldsO[128*32];               // [n_local][d]  16 KB
    __shared__ float ldsZ[128*2];                // [n_local][{z1m,zs}]

    bf16x8 qf0 = *(const bf16x8*)(qh + (size_t)(n0 + ln)*HD_ + 8*hi);
    bf16x8 qf1 = *(const bf16x8*)(qh + (size_t)(n0 + ln)*HD_ + 16 + 8*hi);

    f32x16 O; f32x16 Zc;
    #pragma unroll
    for (int i = 0; i < 16; ++i) { O[i] = 0.f; Zc[i] = 0.f; }

    bf16x8 ka0 = *(const bf16x8*)(kf);
    bf16x8 ka1 = *(const bf16x8*)(kf + 512);
    bf16x8 vf0 = *(const bf16x8*)(vf);
    bf16x8 vf1 = *(const bf16x8*)(vf + 512);
    bf16x8 zf0 = *(const bf16x8*)(zf);
    bf16x8 zf1 = *(const bf16x8*)(zf + 512);

    for (int mt = 0; mt < 16; ++mt) {
        f32x16 S;
        #pragma unroll
        for (int i = 0; i < 16; ++i) S[i] = 0.f;
        __builtin_amdgcn_s_setprio(1);
        S = MFMA32(ka0, qf0, S);
        S = MFMA32(ka1, qf1, S);
        __builtin_amdgcn_s_setprio(0);

        const size_t o1 = (size_t)(mt < 15 ? mt + 1 : mt) * 1024;
        bf16x8 nka0 = *(const bf16x8*)(kf + o1);
        bf16x8 nka1 = *(const bf16x8*)(kf + o1 + 512);
        bf16x8 nvf0 = *(const bf16x8*)(vf + o1);
        bf16x8 nvf1 = *(const bf16x8*)(vf + o1 + 512);
        bf16x8 nzf0 = *(const bf16x8*)(zf + o1);
        bf16x8 nzf1 = *(const bf16x8*)(zf + o1 + 512);

        float e[16];
        #pragma unroll
        for (int i = 0; i < 16; ++i) e[i] = exp2f(S[i]);

        unsigned int x01 = cvtpk(e[0], e[1]), x23 = cvtpk(e[2], e[3]);
        unsigned int x45 = cvtpk(e[4], e[5]), x67 = cvtpk(e[6], e[7]);
        u32x2 r02 = __builtin_amdgcn_permlane32_swap(x01, x45, false, false);
        u32x2 r13 = __builtin_amdgcn_permlane32_swap(x23, x67, false, false);
        u32x4 p0u = { r02[0], r13[0], r02[1], r13[1] };
        bf16x8 pa0 = *reinterpret_cast<bf16x8*>(&p0u);
        unsigned int y01 = cvtpk(e[8], e[9]),  y23 = cvtpk(e[10], e[11]);
        unsigned int y45 = cvtpk(e[12], e[13]), y67 = cvtpk(e[14], e[15]);
        u32x2 s02 = __builtin_amdgcn_permlane32_swap(y01, y45, false, false);
        u32x2 s13 = __builtin_amdgcn_permlane32_swap(y23, y67, false, false);
        u32x4 p1u = { s02[0], s13[0], s02[1], s13[1] };
        bf16x8 pa1 = *reinterpret_cast<bf16x8*>(&p1u);

        __builtin_amdgcn_s_setprio(1);
        O  = MFMA32(pa0, vf0, O);
        O  = MFMA32(pa1, vf1, O);
        Zc = MFMA32(pa0, zf0, Zc);
        Zc = MFMA32(pa1, zf1, Zc);
        __builtin_amdgcn_s_setprio(0);

        ka0 = nka0; ka1 = nka1; vf0 = nvf0; vf1 = nvf1; zf0 = nzf0; zf1 = nzf1;
    }

    // ---- combine the 2 m-halves via LDS ----
    if (sp == 1) {
        #pragma unroll
        for (int r = 0; r < 16; ++r) {
            int nl = nh*32 + (r&3) + 8*(r>>2) + 4*hi;
            ldsO[nl*32 + ln] = O[r];
        }
        if (ln < 2) {
            #pragma unroll
            for (int r = 0; r < 16; ++r) {
                int nl = nh*32 + (r&3) + 8*(r>>2) + 4*hi;
                ldsZ[nl*2 + ln] = Zc[r];
            }
        }
    }
    __syncthreads();
    if (sp == 0) {
        #pragma unroll
        for (int r = 0; r < 16; ++r) {
            int nl = nh*32 + (r&3) + 8*(r>>2) + 4*hi;
            O[r] += ldsO[nl*32 + ln];
            if (ln < 2) Zc[r] += ldsZ[nl*2 + ln];
        }

        const float gs = 1.f / (1.f + __expf(-gating[h]));
        #pragma unroll
        for (int r = 0; r < 16; ++r) {
            const int n = n0 + (r&3) + 8*(r>>2) + 4*hi;
            float z1m = __shfl(Zc[r], (L & 32) | 0);
            float zsv = __shfl(Zc[r], (L & 32) | 1);
            const float* a2p = a2 + (bh*N_ + n)*A2S;
            float z2m = a2p[32];
            float zp  = se1[h*32 + (n & 31)] * se2[h*32 + (n >> 5)];
            float w1  = (1.f - gs) / zsv;
            float w2  = gs / zp;
            float inv = 1.f / (w1*z1m + w2*z2m);
            float o = (w1*O[r] + w2*a2p[ln]) * inv;
            // fragment-major obf write: element (n, c=h*32+ln)
            size_t oaddr = ((size_t)b*64 + (n >> 4))*4096 + (size_t)h*512
                         + (size_t)((ln >> 3)*16 + (n & 15))*8 + (ln & 7);
            ob[oaddr] = __float2bfloat16(o);
        }
    }
}

// ---------------------------------------------------------------------------
// Kernel 5: output projection on MFMA.  A (wpfm) and B (obf) both
// fragment-major -> all loads coalesced 1KB instructions.
// ---------------------------------------------------------------------------
__global__ __launch_bounds__(256) void k_proj_mfma(
    const __hip_bfloat16* __restrict__ obf, const __hip_bfloat16* __restrict__ wpfm,
    const float* __restrict__ bp, float* __restrict__ out)
{
    const int t = threadIdx.x, w = t >> 6, L = t & 63, lo = L & 15, g = L >> 4;
    const int cw = blockIdx.x * 64 + w * 16;
    const int n0 = blockIdx.y * 64, b = blockIdx.z;

    const __hip_bfloat16* afm = wpfm + (size_t)(cw >> 4)*4096 + (size_t)L*8;
    bf16x8 af[8];
    #pragma unroll
    for (int ks = 0; ks < 8; ++ks) af[ks] = *(const bf16x8*)(afm + ks*512);

    const f32x4 Z = {0.f,0.f,0.f,0.f};
    f32x4 D0 = Z, D1 = Z, D2 = Z, D3 = Z;
    const __hip_bfloat16* xb = obf + ((size_t)b*64 + (n0 >> 4))*4096 + (size_t)L*8;
    #pragma unroll
    for (int ks = 0; ks < 8; ++ks) {
        bf16x8 b0 = *(const bf16x8*)(xb + ks*512);
        bf16x8 b1 = *(const bf16x8*)(xb + 4096 + ks*512);
        bf16x8 b2 = *(const bf16x8*)(xb + 8192 + ks*512);
        bf16x8 b3 = *(const bf16x8*)(xb + 12288 + ks*512);
        D0 = MFMA16(af[ks], b0, D0);
        D1 = MFMA16(af[ks], b1, D1);
        D2 = MFMA16(af[ks], b2, D2);
        D3 = MFMA16(af[ks], b3, D3);
    }
    f32x4 D[4] = {D0, D1, D2, D3};

    float bias[4];
    #pragma unroll
    for (int r = 0; r < 4; ++r) bias[r] = bp[cw + 4*g + r];
    #pragma unroll
    for (int nt = 0; nt < 4; ++nt) {
        int nn = n0 + nt*16 + lo;
        #pragma unroll
        for (int r = 0; r < 4; ++r)
            out[((size_t)b*C_ + cw + 4*g + r)*N_ + nn] = D[nt][r] + bias[r];
    }
}

// ---------------------------------------------------------------------------
extern "C" void kernel_launch(void* const* d_in, const int* in_sizes, int n_in,
                              void* d_out, int out_size, void* d_ws, size_t ws_size,
                              hipStream_t stream)
{
    (void)in_sizes; (void)n_in; (void)out_size; (void)ws_size;
    const float* x      = (const float*)d_in[0];
    const float* mask   = (const float*)d_in[1];
    const float* Wqk    = (const float*)d_in[2];
    const float* Wv     = (const float*)d_in[3];
    const float* Wproj  = (const float*)d_in[4];
    const float* bproj  = (const float*)d_in[5];
    const float* Wpos   = (const float*)d_in[6];
    const float* bpos   = (const float*)d_in[7];
    const float* gating = (const float*)d_in[8];
    float* out = (float*)d_out;
    char* w = (char*)d_ws;

    float*          vbuf  = (float*)(w + OFF_VB);
    __hip_bfloat16* qbf   = (__hip_bfloat16*)(w + OFF_QBF);
    __hip_bfloat16* kfrag = (__hip_bfloat16*)(w + OFF_KFR);
    __hip_bfloat16* vfrag = (__hip_bfloat16*)(w + OFF_VFR);
    float*          e1    = (float*)(w + OFF_E1);
    float*          e2    = (float*)(w + OFF_E2);
    float*          se1   = (float*)(w + OFF_SE1);
    float*          se2   = (float*)(w + OFF_SE2);
    float*          a2    = (float*)(w + OFF_A2);
    __hip_bfloat16* obf   = (__hip_bfloat16*)(w + OFF_O);
    __hip_bfloat16* xfm   = (__hip_bfloat16*)(w + OFF_O);   // alias: lifetime disjoint
    __hip_bfloat16* wfm   = (__hip_bfloat16*)(w + OFF_WBF);
    __hip_bfloat16* wpfm  = (__hip_bfloat16*)(w + OFF_WPBF);
    __hip_bfloat16* zfrag = (__hip_bfloat16*)(w + OFF_ZFR);

    k_prep<<<dim3(904), dim3(256), 0, stream>>>(Wqk, Wv, Wproj, mask, Wpos, bpos, x,
                                                wfm, wpfm, zfrag, xfm, e1, e2, se1, se2);
    k_qkv_mfma<<<dim3(12,16,8), dim3(256), 0, stream>>>(xfm, wfm, mask, qbf, kfrag, vfrag, vbuf);
    k_pos_apply<<<dim3(32,8,8), dim3(256), 0, stream>>>(vbuf, mask, e1, e2, a2);
    k_attn_mfma<<<dim3(512), dim3(512), 0, stream>>>(qbf, kfrag, vfrag, zfrag, a2, se1, se2, gating, obf);
    k_proj_mfma<<<dim3(4,16,8), dim3(256), 0, stream>>>(obf, wpfm, bproj, out);
}